// Round 5
// baseline (82.241 us; speedup 1.0000x reference)
//
#include <hip/hip_runtime.h>

constexpr int V  = 50257;   // vocab
constexpr int D  = 300;     // vocab dim
constexpr int KD = 512;     // decoder dim
constexpr int B  = 16;      // batch

constexpr int ROWS = 64;                      // rows per k_att block
constexpr int NB_ATT = (V + ROWS - 1) / ROWS; // 786 blocks
constexpr int NT = 10;                        // d-tiles of 32 (D padded to 320)
constexpr int NC  = 512;                      // wsum chunks
constexpr int RPC = (V + NC - 1) / NC;        // 99 rows per chunk

constexpr float NEG_HUGE = -1.0e30f;

// ws layout (float offsets)
constexpr size_t WS_QT   = 0;                              // 4800
constexpr size_t WS_STAT = 4800;                           // NB_ATT*32
constexpr size_t WS_MS   = WS_STAT + (size_t)NB_ATT * 32;  // 32
constexpr size_t WS_PART = WS_MS + 32;                     // NC*4800
constexpr size_t WS_TMP  = WS_PART + (size_t)NC * 4800;    // 16*4800

struct f4 { float v[4]; };
__device__ __forceinline__ f4 ld4(const float* p) {
    float4 t = *(const float4*)p;
    return {t.x, t.y, t.z, t.w};
}

#define AS1 __attribute__((address_space(1)))
#define AS3 __attribute__((address_space(3)))

// ---------------------------------------------------------------------------
// K1: q_t[d*16+b] = sum_k dh[b,k]*Wdec[d,k] + bdec[d].  One wave per output.
__global__ void __launch_bounds__(256) k_query(
    const float* __restrict__ dh, const float* __restrict__ Wdec,
    const float* __restrict__ bdec, float* __restrict__ q_t)
{
    int wid  = (blockIdx.x * 256 + threadIdx.x) >> 6;
    int lane = threadIdx.x & 63;
    if (wid >= D * B) return;
    int d = wid >> 4, b = wid & 15;
    const float* wrow = Wdec + (size_t)d * KD;
    const float* hrow = dh + (size_t)b * KD;
    float s = 0.f;
    for (int k = lane; k < KD; k += 64) s += wrow[k] * hrow[k];
    #pragma unroll
    for (int off = 32; off; off >>= 1) s += __shfl_down(s, off, 64);
    if (lane == 0) q_t[d * 16 + b] = s + bdec[d];
}

// ---------------------------------------------------------------------------
// K2: att[b,v] = sum_d relu(E[v,d]+q[b,d])*wf[d] + bf.
// Block = 64 rows, 256 threads. Thread t: rows v0+(t>>3), +32; d-slice
// (t&7)*4 within each 32-d tile; ALL 16 batches.
// E staged via global_load_lds into 3 LDS buffers, counted vmcnt(2) pipeline
// (prefetch distance 2 tiles). Thread reads back its OWN linear 16B slot ->
// conflict-free, and E is loaded once per block (not once per wave).
__global__ void __launch_bounds__(256) k_att(
    const float* __restrict__ E, const float* __restrict__ q_t,
    const float* __restrict__ wf, const float* __restrict__ bf,
    float* __restrict__ att, float* __restrict__ blkstats)
{
    __shared__ float se[3 * 2048];   // 3 bufs x 64 rows x 32 d
    __shared__ float sq[5120];       // 320 d x 16 b, quad-rotated, zero-padded
    __shared__ float sw[320];
    __shared__ float smsM[64], smsS[64];

    const int t = threadIdx.x;

    // stage q (rotation: quad col = (bq + (d>>2)) & 3), zero pad d>=300
    for (int i4 = t * 4; i4 < 5120; i4 += 1024) {
        float4 qv = make_float4(0.f, 0.f, 0.f, 0.f);
        if (i4 < 4800) qv = *(const float4*)(q_t + i4);
        int d = i4 >> 4, bq = (i4 & 15) >> 2;
        int col = (bq + (d >> 2)) & 3;
        *(float4*)(sq + (d << 4) + (col << 2)) = qv;
    }
    for (int i = t; i < 320; i += 256) sw[i] = (i < D) ? wf[i] : 0.f;
    __syncthreads();

    const int v0   = blockIdx.x * ROWS;
    const int slot = t & 7;            // d-part 0..7 within tile
    const int s4   = slot << 2;
    const int rloc = t >> 3;           // 0..31
    const int r0   = v0 + rloc;
    const int r1   = r0 + 32;
    const bool va0 = r0 < V, va1 = r1 < V;
    const float* src0 = E + (size_t)(va0 ? r0 : (V - 1)) * D;
    const float* src1 = E + (size_t)(va1 ? r1 : (V - 1)) * D;

    float acc0[16], acc1[16];
    #pragma unroll
    for (int b = 0; b < 16; ++b) { acc0[b] = 0.f; acc1[b] = 0.f; }

#define STAGE(TT, BI) do {                                                    \
    int dd = (TT) * 32 + s4;                                                  \
    if (dd >= D) dd = 0;                                                      \
    float* lb = se + (BI) * 2048 + (t << 2);                                  \
    __builtin_amdgcn_global_load_lds((const AS1 void*)(src0 + dd),            \
                                     (AS3 void*)lb, 16, 0, 0);                \
    __builtin_amdgcn_global_load_lds((const AS1 void*)(src1 + dd),            \
                                     (AS3 void*)(lb + 1024), 16, 0, 0);       \
} while (0)

#define COMPUTE(TT, BI) do {                                                  \
    const float* buf = se + (BI) * 2048;                                      \
    f4 e0 = ld4(buf + (t << 2));                                              \
    f4 e1 = ld4(buf + (t << 2) + 1024);                                       \
    int dbase = (TT) * 32 + s4;                                               \
    _Pragma("unroll")                                                         \
    for (int i = 0; i < 4; ++i) {                                             \
        int d = dbase + i;                                                    \
        float wi = sw[d];                                                     \
        const float* qrow = sq + (d << 4);                                    \
        int rr = d >> 2;                                                      \
        _Pragma("unroll")                                                     \
        for (int bq = 0; bq < 4; ++bq) {                                      \
            f4 qv = ld4(qrow + (((bq + rr) & 3) << 2));                       \
            _Pragma("unroll")                                                 \
            for (int bl = 0; bl < 4; ++bl) {                                  \
                acc0[bq * 4 + bl] = fmaf(fmaxf(e0.v[i] + qv.v[bl], 0.f), wi,  \
                                         acc0[bq * 4 + bl]);                  \
                acc1[bq * 4 + bl] = fmaf(fmaxf(e1.v[i] + qv.v[bl], 0.f), wi,  \
                                         acc1[bq * 4 + bl]);                  \
            }                                                                 \
        }                                                                     \
    }                                                                         \
} while (0)

    STAGE(0, 0);
    STAGE(1, 1);
    for (int tt = 0; tt < NT - 1; ++tt) {
        asm volatile("s_waitcnt vmcnt(2)" ::: "memory");
        __builtin_amdgcn_s_barrier();
        __builtin_amdgcn_sched_barrier(0);
        if (tt < NT - 2) STAGE(tt + 2, (tt + 2) % 3);
        COMPUTE(tt, tt % 3);
    }
    asm volatile("s_waitcnt vmcnt(0)" ::: "memory");
    __builtin_amdgcn_s_barrier();
    __builtin_amdgcn_sched_barrier(0);
    COMPUTE(NT - 1, (NT - 1) % 3);

    // reduce the 8 d-slices of each row (lanes xor 1,2,4)
    #pragma unroll
    for (int b = 0; b < 16; ++b) {
        float x0 = acc0[b], x1 = acc1[b];
        x0 += __shfl_xor(x0, 1, 64); x1 += __shfl_xor(x1, 1, 64);
        x0 += __shfl_xor(x0, 2, 64); x1 += __shfl_xor(x1, 2, 64);
        x0 += __shfl_xor(x0, 4, 64); x1 += __shfl_xor(x1, 4, 64);
        acc0[b] = x0; acc1[b] = x1;
    }

    // lane (slot) owns batches 2*slot, 2*slot+1 for its two rows
    float bfull = bf[0];
    int b0 = slot * 2;
    float v00 = acc0[b0]     + bfull;
    float v01 = acc0[b0 + 1] + bfull;
    float v10 = acc1[b0]     + bfull;
    float v11 = acc1[b0 + 1] + bfull;
    if (va0) {
        att[(size_t)b0 * V + r0]       = v00;
        att[(size_t)(b0 + 1) * V + r0] = v01;
    }
    if (va1) {
        att[(size_t)b0 * V + r1]       = v10;
        att[(size_t)(b0 + 1) * V + r1] = v11;
    }
    // per-batch (m,s) over this lane's 2 rows
    float m0 = fmaxf(va0 ? v00 : NEG_HUGE, va1 ? v10 : NEG_HUGE);
    float m1 = fmaxf(va0 ? v01 : NEG_HUGE, va1 ? v11 : NEG_HUGE);
    float s0 = (va0 ? __expf(v00 - m0) : 0.f) + (va1 ? __expf(v10 - m0) : 0.f);
    float s1 = (va0 ? __expf(v01 - m1) : 0.f) + (va1 ? __expf(v11 - m1) : 0.f);

    // merge across the 8 row-groups of the wave (masks 8,16,32)
    #pragma unroll
    for (int mask = 8; mask <= 32; mask <<= 1) {
        float mo = __shfl_xor(m0, mask, 64), so = __shfl_xor(s0, mask, 64);
        float mn = fmaxf(m0, mo);
        s0 = s0 * __expf(m0 - mn) + so * __expf(mo - mn); m0 = mn;
        mo = __shfl_xor(m1, mask, 64); so = __shfl_xor(s1, mask, 64);
        mn = fmaxf(m1, mo);
        s1 = s1 * __expf(m1 - mn) + so * __expf(mo - mn); m1 = mn;
    }
    int wv = t >> 6;
    if ((t & 63) < 8) {
        smsM[wv * 16 + b0] = m0;     smsS[wv * 16 + b0] = s0;
        smsM[wv * 16 + b0 + 1] = m1; smsS[wv * 16 + b0 + 1] = s1;
    }
    __syncthreads();
    if (t < 16) {
        float m = smsM[t], s = smsS[t];
        #pragma unroll
        for (int w = 1; w < 4; ++w) {
            float mo = smsM[w * 16 + t], so = smsS[w * 16 + t];
            float mn = fmaxf(m, mo);
            s = s * __expf(m - mn) + so * __expf(mo - mn);
            m = mn;
        }
        blkstats[((size_t)blockIdx.x * 16 + t) * 2]     = m;
        blkstats[((size_t)blockIdx.x * 16 + t) * 2 + 1] = s;
    }
#undef STAGE
#undef COMPUTE
}

// ---------------------------------------------------------------------------
// K3: combine per-block stats -> M_b, 1/S_b
__global__ void __launch_bounds__(64) k_combine(
    const float* __restrict__ blkstats, float* __restrict__ MS)
{
    int b = blockIdx.x, lane = threadIdx.x;
    float m = NEG_HUGE;
    for (int c = lane; c < NB_ATT; c += 64)
        m = fmaxf(m, blkstats[(size_t)(c * 16 + b) * 2]);
    #pragma unroll
    for (int off = 32; off; off >>= 1) m = fmaxf(m, __shfl_xor(m, off, 64));
    float s = 0.f;
    for (int c = lane; c < NB_ATT; c += 64)
        s += blkstats[(size_t)(c * 16 + b) * 2 + 1] *
             __expf(blkstats[(size_t)(c * 16 + b) * 2] - m);
    #pragma unroll
    for (int off = 32; off; off >>= 1) s += __shfl_xor(s, off, 64);
    if (lane == 0) { MS[b * 2] = m; MS[b * 2 + 1] = 1.f / s; }
}

// ---------------------------------------------------------------------------
// K4 (fused alpha + wsum): per chunk c of RPC rows:
//   phase 1: alpha = exp(att-M)*invS, written in place AND staged in LDS
//   phase 2: thread t<300 owns column d=t, accumulates 16 batch partials.
__global__ void __launch_bounds__(320) k_awsum(
    const float* __restrict__ E, float* __restrict__ att,
    const float* __restrict__ MS, float* __restrict__ partials)
{
    __shared__ float sal[RPC * 16];   // [vv][b]
    int c = blockIdx.x, t = threadIdx.x;
    int v0 = c * RPC;
    int n = V - v0;
    if (n > RPC) n = RPC;
    if (n < 0) n = 0;

    for (int i = t; i < RPC * 16; i += 320) {
        int b = i / RPC, vv = i - b * RPC;
        float a = 0.f;
        if (vv < n) {
            float M = MS[b * 2], invS = MS[b * 2 + 1];
            size_t gi = (size_t)b * V + v0 + vv;
            a = __expf(att[gi] - M) * invS;
            att[gi] = a;
        }
        sal[vv * 16 + b] = a;
    }
    __syncthreads();

    if (t < D) {
        float acc[16];
        #pragma unroll
        for (int b = 0; b < 16; ++b) acc[b] = 0.f;
        #pragma unroll 4
        for (int vv = 0; vv < n; ++vv) {
            float e = E[(size_t)(v0 + vv) * D + t];
            const float* ap = sal + vv * 16;
            f4 a0 = ld4(ap), a1 = ld4(ap + 4), a2 = ld4(ap + 8), a3 = ld4(ap + 12);
            #pragma unroll
            for (int b = 0; b < 4; ++b) {
                acc[b]      = fmaf(a0.v[b], e, acc[b]);
                acc[b + 4]  = fmaf(a1.v[b], e, acc[b + 4]);
                acc[b + 8]  = fmaf(a2.v[b], e, acc[b + 8]);
                acc[b + 12] = fmaf(a3.v[b], e, acc[b + 12]);
            }
        }
        #pragma unroll
        for (int b = 0; b < 16; ++b)
            partials[(size_t)c * 4800 + b * D + t] = acc[b];
    }
}

// ---------------------------------------------------------------------------
// K5/K6: two-stage reduction of partials over NC chunks, float4-wide.
__global__ void __launch_bounds__(256) k_red1(
    const float* __restrict__ partials, float* __restrict__ tmp)
{
    int o4 = blockIdx.x * 256 + threadIdx.x;   // quad index, 1200 total
    if (o4 >= 1200) return;
    int y = blockIdx.y;
    float4 s = {0.f, 0.f, 0.f, 0.f};
    for (int c = y * 32; c < y * 32 + 32; ++c) {
        float4 p = *(const float4*)(partials + (size_t)c * 4800 + o4 * 4);
        s.x += p.x; s.y += p.y; s.z += p.z; s.w += p.w;
    }
    *(float4*)(tmp + (size_t)y * 4800 + o4 * 4) = s;
}

__global__ void __launch_bounds__(256) k_red2(
    const float* __restrict__ tmp, float* __restrict__ out)
{
    int o4 = blockIdx.x * 256 + threadIdx.x;
    if (o4 >= 1200) return;
    float4 s = {0.f, 0.f, 0.f, 0.f};
    #pragma unroll
    for (int y = 0; y < 16; ++y) {
        float4 p = *(const float4*)(tmp + (size_t)y * 4800 + o4 * 4);
        s.x += p.x; s.y += p.y; s.z += p.z; s.w += p.w;
    }
    *(float4*)(out + o4 * 4) = s;
}

// ---------------------------------------------------------------------------
extern "C" void kernel_launch(void* const* d_in, const int* in_sizes, int n_in,
                              void* d_out, int out_size, void* d_ws, size_t ws_size,
                              hipStream_t stream) {
    const float* dh   = (const float*)d_in[0];
    const float* E    = (const float*)d_in[1];
    const float* Wdec = (const float*)d_in[2];
    const float* bdec = (const float*)d_in[3];
    const float* wf   = (const float*)d_in[4];
    const float* bf   = (const float*)d_in[5];
    float* out = (float*)d_out;          // enc [0,4800), alpha [4800, ...)
    float* ws  = (float*)d_ws;

    float* q_t   = ws + WS_QT;
    float* stats = ws + WS_STAT;
    float* MS    = ws + WS_MS;
    float* part  = ws + WS_PART;
    float* tmp   = ws + WS_TMP;
    float* att   = out + 4800;

    k_query<<<(D * B + 3) / 4, 256, 0, stream>>>(dh, Wdec, bdec, q_t);
    k_att<<<NB_ATT, 256, 0, stream>>>(E, q_t, wf, bf, att, stats);
    k_combine<<<B, 64, 0, stream>>>(stats, MS);
    k_awsum<<<NC, 320, 0, stream>>>(E, att, MS, part);
    k_red1<<<dim3(5, 16), 256, 0, stream>>>(part, tmp);
    k_red2<<<5, 256, 0, stream>>>(tmp, out);
}